// Round 8
// baseline (187.755 us; speedup 1.0000x reference)
//
#include <hip/hip_runtime.h>

// FD_discretizer on fixed 1024x1024 grid, Ex=Ey=1026 extended grid.
// Round 8: ONE uniform kernel, no slow path. 2048 blocks tile the full
// 1024x1024 output (64x8 per block). Each block stages a 10x66 halo tile in
// EXT coordinates; ghost-ring values (ext rows/cols 0 and 1025) are computed
// in-line with near-wave-uniform branches (bottom/top halo rows are whole-row
// uniform; left/right ghosts touch 1-2 lanes/row in 256 of 2048 blocks).
// Phase 1 computes per-node derived quantities once into SoA LDS planes;
// phase 2 (unchanged from R7, verified) computes 2 outputs/thread from LDS.
// Rationale: R4-R7 totals pinned at ~181-183 regardless of fast-path
// structure -> the 24 divergent-gather slow blocks were the critical path
// (R2 measured ~16us/block for that code). This removes them entirely.

#define NXC 1024               // NX == NY
#define EXC 1026               // Ex == Ey
#define NN  (NXC*NXC)

#define TB_ROWS 8
#define TB_COLS 64
#define H_ROWS  10             // TB_ROWS + 2
#define H_COLS  66             // TB_COLS + 2
#define NNODE   (H_ROWS*H_COLS)   // 660

// LDS plane ids
#define P_U   0
#define P_V   1
#define P_P   2
#define P_UO  3
#define P_VO  4
#define P_CU  5     // contravariant U (new)
#define P_CV  6     // contravariant V (new)
#define P_CUO 7
#define P_CVO 8
#define P_A11 9
#define P_A22 10
#define P_PQX 11
#define P_PQY 12
#define P_PEX 13
#define P_PEY 14
#define P_RJ  15

extern "C" __global__ void __launch_bounds__(256)
fd_kernel(const float* __restrict__ uvp,     // original_uv  n x 3
          const float* __restrict__ uvo,     // uv_old       n x 3
          const float* __restrict__ ndy,     // node_y       n x 3
          const float* __restrict__ ebm,     // ext metrics  n_ext x 5
          const float* __restrict__ dtg,     // dt           1
          const float* __restrict__ th,      // pde_theta    5
          const float* __restrict__ rl,      // relaxation   1
          float* __restrict__ out)
{
  const int bid = blockIdx.x;
  const int tid = threadIdx.x;

  const float dt   = dtg[0];
  const float uc   = th[0], cc = th[1], convc = th[2], pc = th[3], dc = th[4];
  const float relax= rl[0];
  const float rdt  = 1.f/dt;

  __shared__ float sm[16][NNODE];            // 16 SoA planes, 42.24 KB

  const int ctl = bid & 15, rt = bid >> 4;   // 16 col tiles x 128 row tiles
  const int X0e = ctl*TB_COLS;               // halo ext col base (0..960)
  const int J0e = rt*TB_ROWS;                // halo ext row base (0..1016)

  // ---- phase 1: stage 10x66 ext-halo nodes; BC ghosts computed in-line ----
  #pragma unroll
  for (int it=0; it<3; ++it){
    const int idx = tid + it*256;
    if (idx < NNODE){
      const int r  = idx / H_COLS;
      const int c  = idx - r*H_COLS;
      const int je = J0e + r;                // ext row in [0,1025]
      const int ie = X0e + c;                // ext col in [0,1025]
      const bool gB=(je==0), gT=(je==EXC-1), gL=(ie==0), gR=(ie==EXC-1);
      const bool onx=gL|gR, ony=gB|gT;

      float u,v,p,uo,vo;
      if (!(onx|ony)){
        // interior ext node: raw field value (+ press-point on new field)
        const int g3 = 3*((je-1)*NXC + (ie-1));
        u=uvp[g3]; v=uvp[g3+1]; p=uvp[g3+2];
        uo=uvo[g3]; vo=uvo[g3+1];
        if (je==EXC/2 && ie==EXC/2) p = 0.f;           // PRESS_POINT (513,513)
      } else if (onx & ony){
        // corner: clipped interior, never ghost-updated
        const int io = gL?0:NXC-1, jo = gB?0:NXC-1;
        const int g3 = 3*(jo*NXC+io);
        u=uvp[g3]; v=uvp[g3+1]; p=uvp[g3+2];
        uo=uvo[g3]; vo=uvo[g3+1];
      } else if (ony){
        // bottom/top WALL ghost: uv mirrored through dummy at g1; p from g2
        const int io = ie-1;                           // in [0,1023]
        const int j1 = gB?0:NXC-1, j2 = gB?1:NXC-2;
        const int m1 = 3*(j1*NXC+io), m2 = 3*(j2*NXC+io);
        const bool useF = (io==NXC-1);                 // OUTFLOW g1 -> dummy=field
        const float d1u = useF? uvp[m1]   : ndy[m1];
        const float d1v = useF? uvp[m1+1] : ndy[m1+1];
        u = 2.f*d1u - uvp[m2]; v = 2.f*d1v - uvp[m2+1]; p = uvp[m2+2];
        const float e1u = useF? uvo[m1]   : ndy[m1];
        const float e1v = useF? uvo[m1+1] : ndy[m1+1];
        uo = 2.f*e1u - uvo[m2]; vo = 2.f*e1v - uvo[m2+1];
      } else if (gL){
        // left INFLOW ghost: uv mirrored through node_y at col 0; p from col 1
        const int jo = je-1;
        const int m1 = 3*(jo*NXC), m2 = m1+3;
        const float d1u = ndy[m1], d1v = ndy[m1+1];
        u = 2.f*d1u - uvp[m2]; v = 2.f*d1v - uvp[m2+1]; p = uvp[m2+2];
        uo = 2.f*d1u - uvo[m2]; vo = 2.f*d1v - uvo[m2+1];
      } else {
        // right OUTFLOW ghost: uv copied from col 1022; p = -p[1022]
        // (dummy_p at col 1023 is 0 since that whole column is OUTFLOW)
        const int m2 = 3*((je-1)*NXC + NXC-2);
        u = uvp[m2]; v = uvp[m2+1]; p = -uvp[m2+2];
        uo = uvo[m2]; vo = uvo[m2+1];
      }

      // metrics at this ext node (defined on full ext grid, ghosts included)
      const int e5 = 5*(je*EXC + ie);
      const float dxx=ebm[e5], dxy=ebm[e5+1], dex=ebm[e5+2], dey=ebm[e5+3];
      const float rJ = 1.f/ebm[e5+4];

      sm[P_U ][idx]=u;  sm[P_V ][idx]=v;  sm[P_P ][idx]=p;
      sm[P_UO][idx]=uo; sm[P_VO][idx]=vo;
      sm[P_CU ][idx]=(u *dxx + v *dxy)*rJ;
      sm[P_CV ][idx]=(u *dex + v *dey)*rJ;
      sm[P_CUO][idx]=(uo*dxx + vo*dxy)*rJ;
      sm[P_CVO][idx]=(uo*dex + vo*dey)*rJ;
      sm[P_A11][idx]=(dxx*dxx + dxy*dxy)*rJ;
      sm[P_A22][idx]=(dex*dex + dey*dey)*rJ;
      const float pq = p*rJ;
      sm[P_PQX][idx]=pq*dxx; sm[P_PQY][idx]=pq*dxy;
      sm[P_PEX][idx]=pq*dex; sm[P_PEY][idx]=pq*dey;
      sm[P_RJ ][idx]=rJ;
    }
  }
  __syncthreads();

  // ---- phase 2: 2 outputs per thread, all reads from LDS (R7-verified) ----
  const int tx = tid & 63, ty = tid >> 6;
  #pragma unroll
  for (int kk=0; kk<2; ++kk){
    const int r = 1 + ty*2 + kk;             // local halo row of center
    const int c = 1 + tx;                    // local halo col of center
    const int iC = r*H_COLS + c;
    const int iW = iC-1, iE = iC+1, iS = iC-H_COLS, iN = iC+H_COLS;

    const float UC=sm[P_CU][iC], UW=sm[P_CU][iW], UE=sm[P_CU][iE];
    const float VC=sm[P_CV][iC], VS=sm[P_CV][iS], VN=sm[P_CV][iN];
    const float UCo=sm[P_CUO][iC], UWo=sm[P_CUO][iW], UEo=sm[P_CUO][iE];
    const float VCo=sm[P_CVO][iC], VSo=sm[P_CVO][iS], VNo=sm[P_CVO][iN];

    const float Ufl =0.5f*(UW +UC ), Ufr =0.5f*(UC +UE );
    const float Vfd =0.5f*(VS +VC ), Vfu =0.5f*(VC +VN );
    const float Uflo=0.5f*(UWo+UCo), Ufro=0.5f*(UCo+UEo);
    const float Vfdo=0.5f*(VSo+VCo), Vfuo=0.5f*(VCo+VNo);

    const float loss = (Ufr - Ufl + Vfu - Vfd) * cc;

    const float u_c=sm[P_U][iC], v_c=sm[P_V][iC];
    const float uW =sm[P_U][iW], vW =sm[P_V][iW];
    const float uE =sm[P_U][iE], vE =sm[P_V][iE];
    const float uS =sm[P_U][iS], vS =sm[P_V][iS];
    const float uN =sm[P_U][iN], vN =sm[P_V][iN];

    const float cnu = 0.5f*(u_c+uE)*Ufr - 0.5f*(uW+u_c)*Ufl
                    + 0.5f*(u_c+uN)*Vfu - 0.5f*(uS+u_c)*Vfd;
    const float cnv = 0.5f*(v_c+vE)*Ufr - 0.5f*(vW+v_c)*Ufl
                    + 0.5f*(v_c+vN)*Vfu - 0.5f*(vS+v_c)*Vfd;

    const float uoc=sm[P_UO][iC], voc=sm[P_VO][iC];
    const float uoW=sm[P_UO][iW], voW=sm[P_VO][iW];
    const float uoE=sm[P_UO][iE], voE=sm[P_VO][iE];
    const float uoS=sm[P_UO][iS], voS=sm[P_VO][iS];
    const float uoN=sm[P_UO][iN], voN=sm[P_VO][iN];

    const float cou = 0.5f*(uoc+uoE)*Ufro - 0.5f*(uoW+uoc)*Uflo
                    + 0.5f*(uoc+uoN)*Vfuo - 0.5f*(uoS+uoc)*Vfdo;
    const float cov = 0.5f*(voc+voE)*Ufro - 0.5f*(voW+voc)*Uflo
                    + 0.5f*(voc+voN)*Vfuo - 0.5f*(voS+voc)*Vfdo;

    const float convu = relax*cou + (1.f-relax)*cnu;
    const float convv = relax*cov + (1.f-relax)*cnv;

    const float a11C=sm[P_A11][iC], a11W=sm[P_A11][iW], a11E=sm[P_A11][iE];
    const float a22C=sm[P_A22][iC], a22S=sm[P_A22][iS], a22N=sm[P_A22][iN];
    const float du = 0.5f*(a11C+a11E)*(uE-u_c) - 0.5f*(a11W+a11C)*(u_c-uW)
                   + 0.5f*(a22C+a22N)*(uN-u_c) - 0.5f*(a22S+a22C)*(u_c-uS);
    const float dv = 0.5f*(a11C+a11E)*(vE-v_c) - 0.5f*(a11W+a11C)*(v_c-vW)
                   + 0.5f*(a22C+a22N)*(vN-v_c) - 0.5f*(a22S+a22C)*(v_c-vS);

    const float gPx = 0.5f*(sm[P_PQX][iE]-sm[P_PQX][iW]) + 0.5f*(sm[P_PEX][iN]-sm[P_PEX][iS]);
    const float gPy = 0.5f*(sm[P_PEY][iN]-sm[P_PEY][iS]) + 0.5f*(sm[P_PQY][iE]-sm[P_PQY][iW]);

    const float rJC = sm[P_RJ][iC];
    const float unst_u = (u_c - uoc)*rdt*rJC;
    const float unst_v = (v_c - voc)*rdt*rJC;

    const float momu = uc*unst_u + convc*convu + pc*gPx - dc*du;
    const float momv = uc*unst_v + convc*convv + pc*gPy - dc*dv;

    // vis: [1 2 1; 2 4 2; 1 2 1]/16 over 3x3
    const float uSW=sm[P_U][iS-1], uSE=sm[P_U][iS+1], uNW=sm[P_U][iN-1], uNE=sm[P_U][iN+1];
    const float vSW=sm[P_V][iS-1], vSE=sm[P_V][iS+1], vNW=sm[P_V][iN-1], vNE=sm[P_V][iN+1];
    const float p_c=sm[P_P][iC];
    const float pW=sm[P_P][iW], pE=sm[P_P][iE], pS=sm[P_P][iS], pN=sm[P_P][iN];
    const float pSW=sm[P_P][iS-1], pSE=sm[P_P][iS+1], pNW=sm[P_P][iN-1], pNE=sm[P_P][iN+1];

    const float visu=(uSW+uSE+uNW+uNE + 2.f*(uS+uW+uE+uN) + 4.f*u_c)*0.0625f;
    const float visv=(vSW+vSE+vNW+vNE + 2.f*(vS+vW+vE+vN) + 4.f*v_c)*0.0625f;
    const float visp=(pSW+pSE+pNW+pNE + 2.f*(pS+pW+pE+pN) + 4.f*p_c)*0.0625f;

    const int j = rt*TB_ROWS + ty*2 + kk;    // output row in [0,1023]
    const int o = j*NXC + X0e + tx;          // output col = X0e + tx
    out[o]        = loss;
    out[NN + o]   = momu;
    out[2*NN + o] = momv;
    const int vb = 3*NN + 3*o;
    out[vb]   = visu;
    out[vb+1] = visv;
    out[vb+2] = visp;
  }
}

extern "C" void kernel_launch(void* const* d_in, const int* in_sizes, int n_in,
                              void* d_out, int out_size, void* d_ws, size_t ws_size,
                              hipStream_t stream) {
  const float* uvp = (const float*)d_in[0];   // original_uv
  const float* uvo = (const float*)d_in[1];   // uv_old
  const float* ndy = (const float*)d_in[2];   // node_y
  const float* ebm = (const float*)d_in[4];   // extended_block_metrics
  const float* dtg = (const float*)d_in[5];   // dt_graph
  const float* th  = (const float*)d_in[6];   // pde_theta
  const float* rl  = (const float*)d_in[7];   // relaxtion
  float* out = (float*)d_out;

  // 16 col tiles x 128 row tiles = 2048 uniform blocks, full coverage
  fd_kernel<<<dim3(2048), dim3(256), 0, stream>>>(uvp, uvo, ndy, ebm, dtg, th, rl, out);
}